// Round 1
// baseline (300.833 us; speedup 1.0000x reference)
//
#include <hip/hip_runtime.h>
#include <hip/hip_fp16.h>

#define TW 4      // tokens per wave
#define TB 16     // tokens per block
#define NWAVE 4

typedef unsigned int uint32;

__device__ __forceinline__ float2 up2(uint32 u) {
  __half2 h = *reinterpret_cast<__half2*>(&u);
  return __half22float2(h);
}
__device__ __forceinline__ uint32 pk2(float a, float b) {
  __half2 h = __floats2half2_rn(a, b);
  return *reinterpret_cast<uint32*>(&h);
}
__device__ __forceinline__ float bc(float v, int sl) {  // broadcast from lane sl (uniform)
  return __int_as_float(__builtin_amdgcn_readlane(__float_as_int(v), sl));
}
__device__ __forceinline__ float wred_sum(float v) {
  v += __shfl_xor(v, 32); v += __shfl_xor(v, 16); v += __shfl_xor(v, 8);
  v += __shfl_xor(v, 4);  v += __shfl_xor(v, 2);  v += __shfl_xor(v, 1);
  return v;
}

// ---- staged-weight matvec macros (weights f16-packed pairs over the K dim) ----
// WB[p*128 + j] = pack(W[c0+2p][j], W[c0+2p+1][j]) ; lane owns output cols j=lane, lane+64.

#define STAGE_NAT(W, LDW, C0) do {                                              \
  _Pragma("unroll")                                                             \
  for (int r_ = 0; r_ < 16; ++r_) {                                             \
    int idx_ = r_*256 + tid;                                                    \
    int p_ = idx_ >> 7, j_ = idx_ & 127;                                        \
    int c_ = (C0) + 2*p_;                                                       \
    float f0_ = (W)[(size_t)c_*(LDW) + j_];                                     \
    float f1_ = (W)[(size_t)(c_+1)*(LDW) + j_];                                 \
    WB[idx_] = pk2(f0_, f1_);                                                   \
  } } while(0)

// transposed stage of w_kv k-part: WB[p*128 + i] = pack(wkv[i][C0+2p], wkv[i][C0+2p+1])
#define STAGE_TR(C0) do {                                                       \
  _Pragma("unroll")                                                             \
  for (int r_ = 0; r_ < 8; ++r_) {                                              \
    int f_ = r_*256 + tid;                                                      \
    int i_ = f_ >> 4;                                                           \
    int cq_ = f_ & 15;                                                          \
    float4 v_ = *reinterpret_cast<const float4*>(&wkv[(size_t)i_*256 + (C0) + cq_*4]); \
    WB[(cq_*2)*128 + i_]     = pk2(v_.x, v_.y);                                 \
    WB[(cq_*2 + 1)*128 + i_] = pk2(v_.z, v_.w);                                 \
  } } while(0)

// y[j] += sum_{c in half} in[c] * W[c][j] ; broadcast source held in regs IN[lt] (lane-indexed)
#define MV_HALF(IN, A0, A1) do {                                                \
  _Pragma("unroll 4")                                                           \
  for (int p_ = 0; p_ < 32; ++p_) {                                             \
    uint32 uw0_ = WB[p_*128 + lane];                                            \
    uint32 uw1_ = WB[p_*128 + 64 + lane];                                       \
    float2 wa_ = up2(uw0_), wb_ = up2(uw1_);                                    \
    _Pragma("unroll")                                                           \
    for (int lt_ = 0; lt_ < TW; ++lt_) {                                        \
      float qa_ = bc(IN[lt_], 2*p_);                                            \
      float qb_ = bc(IN[lt_], 2*p_+1);                                          \
      A0[lt_] += qa_*wa_.x; A0[lt_] += qb_*wa_.y;                               \
      A1[lt_] += qa_*wb_.x; A1[lt_] += qb_*wb_.y;                               \
    } } } while(0)

// q-proj variant: broadcast x from LDS (f16)
#define MVX_HALF(A0, A1, C0) do {                                               \
  _Pragma("unroll 4")                                                           \
  for (int p_ = 0; p_ < 32; ++p_) {                                             \
    uint32 uw0_ = WB[p_*128 + lane];                                            \
    uint32 uw1_ = WB[p_*128 + 64 + lane];                                       \
    float2 wa_ = up2(uw0_), wb_ = up2(uw1_);                                    \
    _Pragma("unroll")                                                           \
    for (int lt_ = 0; lt_ < TW; ++lt_) {                                        \
      uint32 ux_ = *reinterpret_cast<const uint32*>(&Xh[(ltb + lt_)*128 + (C0) + 2*p_]); \
      float2 xv_ = up2(ux_);                                                    \
      A0[lt_] += xv_.x*wa_.x; A0[lt_] += xv_.y*wa_.y;                           \
      A1[lt_] += xv_.x*wb_.x; A1[lt_] += xv_.y*wb_.y;                           \
    } } } while(0)

// qw[h][i] = sum_d q[h*32+d] * WkT[h*32+d][i] ; h-blocked (rows 16p..16p+15 share h)
#define QW_HALF(QSRC, HBASE) do {                                               \
  _Pragma("unroll")                                                             \
  for (int hh_ = 0; hh_ < 2; ++hh_) {                                           \
    float a0_[TW] = {0.f,0.f,0.f,0.f};                                          \
    float a1_[TW] = {0.f,0.f,0.f,0.f};                                          \
    _Pragma("unroll 4")                                                         \
    for (int p_ = hh_*16; p_ < hh_*16 + 16; ++p_) {                             \
      uint32 uw0_ = WB[p_*128 + lane];                                          \
      uint32 uw1_ = WB[p_*128 + 64 + lane];                                     \
      float2 wa_ = up2(uw0_), wb_ = up2(uw1_);                                  \
      _Pragma("unroll")                                                         \
      for (int lt_ = 0; lt_ < TW; ++lt_) {                                      \
        float qa_ = bc(QSRC[lt_], 2*p_);                                        \
        float qb_ = bc(QSRC[lt_], 2*p_+1);                                      \
        a0_[lt_] += qa_*wa_.x; a0_[lt_] += qb_*wa_.y;                           \
        a1_[lt_] += qa_*wb_.x; a1_[lt_] += qb_*wb_.y;                           \
      } }                                                                       \
    int h_ = (HBASE) + hh_;                                                     \
    _Pragma("unroll")                                                           \
    for (int lt_ = 0; lt_ < TW; ++lt_) {                                        \
      QWC[((ltb + lt_)*4 + h_)*130 + lane]      = __float2half_rn(a0_[lt_]);    \
      QWC[((ltb + lt_)*4 + h_)*130 + 64 + lane] = __float2half_rn(a1_[lt_]);    \
    } } } while(0)

// out[j] += sum_i ctx[h(j)][i] * Wv[i][j]
#define PV_HALF(A0, A1, C0) do {                                                \
  const int h1_ = lane >> 5, h2_ = 2 + (lane >> 5);                             \
  _Pragma("unroll 4")                                                           \
  for (int p_ = 0; p_ < 32; ++p_) {                                             \
    uint32 uw0_ = WB[p_*128 + lane];                                            \
    uint32 uw1_ = WB[p_*128 + 64 + lane];                                       \
    float2 wa_ = up2(uw0_), wb_ = up2(uw1_);                                    \
    int i_ = (C0) + 2*p_;                                                       \
    _Pragma("unroll")                                                           \
    for (int lt_ = 0; lt_ < TW; ++lt_) {                                        \
      float2 cA_ = up2(*reinterpret_cast<const uint32*>(&QWC[((ltb + lt_)*4 + h1_)*130 + i_])); \
      float2 cB_ = up2(*reinterpret_cast<const uint32*>(&QWC[((ltb + lt_)*4 + h2_)*130 + i_])); \
      A0[lt_] += cA_.x*wa_.x; A0[lt_] += cA_.y*wa_.y;                           \
      A1[lt_] += cB_.x*wb_.x; A1[lt_] += cB_.y*wb_.y;                           \
    } } } while(0)

__global__ void __launch_bounds__(256, 3) ca_fused(
    const float* __restrict__ xq,  const float* __restrict__ kvin,
    const float* __restrict__ wkv, const float* __restrict__ wq,
    const float* __restrict__ wmh, const float* __restrict__ bmh,
    const float* __restrict__ w1,  const float* __restrict__ b1,
    const float* __restrict__ w2,  const float* __restrict__ b2,
    const float* __restrict__ g1,  const float* __restrict__ bb1,
    const float* __restrict__ g2,  const float* __restrict__ bb2,
    float* __restrict__ outp)
{
  __shared__ uint32 WB[32*128];        // 16 KB: staged half-matrix, f16 pairs over K
  __shared__ __half Xh[TB*128];        // 4 KB
  __shared__ __half QWC[TB*4*130];     // 16.25 KB: qw, then ctx (in-place per token)
  __shared__ float  KVS[NWAVE*8*130];  // 16.25 KB: one token's kv rows per wave
  __shared__ float  ATTN[NWAVE*32];    // 0.5 KB

  const int tid  = threadIdx.x;
  const int wv   = tid >> 6;
  const int lane = tid & 63;
  const int tb   = blockIdx.x * TB;
  const int ltb  = wv * TW;

  // ---- load x tile (f16) ----
  {
    const float4* src = reinterpret_cast<const float4*>(xq + (size_t)tb*128);
    _Pragma("unroll")
    for (int r = 0; r < 2; ++r) {
      int i4 = r*256 + tid;
      float4 v = src[i4];
      uint2 u; u.x = pk2(v.x, v.y); u.y = pk2(v.z, v.w);
      *reinterpret_cast<uint2*>(&Xh[i4*4]) = u;
    }
  }

  // ---- P1: q = x @ wq ----
  float q0[TW] = {0.f,0.f,0.f,0.f}, q1[TW] = {0.f,0.f,0.f,0.f};
  __syncthreads(); STAGE_NAT(wq, 128, 0);  __syncthreads();
  MVX_HALF(q0, q1, 0);
  __syncthreads(); STAGE_NAT(wq, 128, 64); __syncthreads();
  MVX_HALF(q0, q1, 64);

  // ---- P2: qw[h][i] = sum_d q[h,d] * wkv[i][h*32+d] ----
  __syncthreads(); STAGE_TR(0);  __syncthreads();
  QW_HALF(q0, 0);
  __syncthreads(); STAGE_TR(64); __syncthreads();
  QW_HALF(q1, 2);

  // ---- P3: per-token attention: sim, softmax, ctx (overwrites qw rows) ----
  const float SCALE = 0.17677669529663687f;  // 1/sqrt(32)
  _Pragma("unroll 1")
  for (int lt = 0; lt < TW; ++lt) {
    const int ltok = ltb + lt;
    const int tok  = tb + ltok;
    __syncthreads();
    {  // load kv rows for this wave's token (fp32)
      const float4* kv4 = reinterpret_cast<const float4*>(kvin + (size_t)tok*1024);
      _Pragma("unroll")
      for (int r = 0; r < 4; ++r) {
        int idx = lane + r*64;
        float4 v = kv4[idx];
        int k = idx >> 5, i4 = (idx & 31)*4;
        float* dst = &KVS[(wv*8 + k)*130 + i4];
        *reinterpret_cast<float2*>(dst)     = make_float2(v.x, v.y);
        *reinterpret_cast<float2*>(dst + 2) = make_float2(v.z, v.w);
      }
    }
    __syncthreads();
    {  // sim + softmax: lane -> (h,k) pair x i-half
      int p = lane & 31, h = p >> 3, k = p & 7, half = lane >> 5;
      const __half* qrow = &QWC[(ltok*4 + h)*130];
      const float*  krow = &KVS[(wv*8 + k)*130];
      float acc = 0.f;
      _Pragma("unroll")
      for (int ii = 0; ii < 32; ++ii) {
        int i = half*64 + 2*ii;
        float2 qv  = up2(*reinterpret_cast<const uint32*>(&qrow[i]));
        float2 kv2 = *reinterpret_cast<const float2*>(&krow[i]);
        acc += qv.x*kv2.x; acc += qv.y*kv2.y;
      }
      acc *= SCALE;
      acc += __shfl_xor(acc, 32);
      float m = acc;
      m = fmaxf(m, __shfl_xor(m, 1));
      m = fmaxf(m, __shfl_xor(m, 2));
      m = fmaxf(m, __shfl_xor(m, 4));
      float e = __expf(acc - m);
      float s = e;
      s += __shfl_xor(s, 1); s += __shfl_xor(s, 2); s += __shfl_xor(s, 4);
      float at = __fdividef(e, s);
      if (lane < 32) ATTN[wv*32 + p] = at;
    }
    __syncthreads();
    {  // ctx[h][i] = sum_k attn[h,k]*kv[k,i]  (write over qw rows, f16)
      float kva[8], kvb[8];
      _Pragma("unroll")
      for (int k = 0; k < 8; ++k) {
        kva[k] = KVS[(wv*8 + k)*130 + lane];
        kvb[k] = KVS[(wv*8 + k)*130 + 64 + lane];
      }
      _Pragma("unroll")
      for (int h = 0; h < 4; ++h) {
        float4 aA = *reinterpret_cast<const float4*>(&ATTN[wv*32 + h*8]);
        float4 aB = *reinterpret_cast<const float4*>(&ATTN[wv*32 + h*8 + 4]);
        float c0a = aA.x*kva[0] + aA.y*kva[1] + aA.z*kva[2] + aA.w*kva[3]
                  + aB.x*kva[4] + aB.y*kva[5] + aB.z*kva[6] + aB.w*kva[7];
        float c1a = aA.x*kvb[0] + aA.y*kvb[1] + aA.z*kvb[2] + aA.w*kvb[3]
                  + aB.x*kvb[4] + aB.y*kvb[5] + aB.z*kvb[6] + aB.w*kvb[7];
        QWC[(ltok*4 + h)*130 + lane]      = __float2half_rn(c0a);
        QWC[(ltok*4 + h)*130 + 64 + lane] = __float2half_rn(c1a);
      }
    }
  }

  // ---- P4: out[j] = sum_i ctx[h(j)][i] * wkv[i][128+j] ----
  float o0[TW] = {0.f,0.f,0.f,0.f}, o1[TW] = {0.f,0.f,0.f,0.f};
  __syncthreads(); STAGE_NAT(wkv + 128, 256, 0);  __syncthreads();
  PV_HALF(o0, o1, 0);
  __syncthreads(); STAGE_NAT(wkv + 128, 256, 64); __syncthreads();
  PV_HALF(o0, o1, 64);

  // ---- P5: y = out @ wmh + bmh ; LN1 ; + x ----
  float y0[TW] = {0.f,0.f,0.f,0.f}, y1[TW] = {0.f,0.f,0.f,0.f};
  __syncthreads(); STAGE_NAT(wmh, 128, 0);  __syncthreads();
  MV_HALF(o0, y0, y1);
  __syncthreads(); STAGE_NAT(wmh, 128, 64); __syncthreads();
  MV_HALF(o1, y0, y1);

  float res0[TW], res1[TW];
  {
    float ba = bmh[lane], bb = bmh[lane + 64];
    float ga = g1[lane],  gb = g1[lane + 64];
    float ca = bb1[lane], cb = bb1[lane + 64];
    _Pragma("unroll")
    for (int lt = 0; lt < TW; ++lt) {
      float v0 = y0[lt] + ba, v1 = y1[lt] + bb;
      float s  = wred_sum(v0 + v1);
      float sq = wred_sum(v0*v0 + v1*v1);
      float mu = s * 0.0078125f;
      float var = sq * 0.0078125f - mu*mu;
      float rstd = rsqrtf(var + 1e-5f);
      int tok = tb + ltb + lt;
      float x0 = xq[(size_t)tok*128 + lane];
      float x1 = xq[(size_t)tok*128 + 64 + lane];
      res0[lt] = (v0 - mu)*rstd*ga + ca + x0;
      res1[lt] = (v1 - mu)*rstd*gb + cb + x1;
    }
  }

  // ---- P6: hmid = gelu(res @ w1 + b1) ----
  float hm0[TW] = {0.f,0.f,0.f,0.f}, hm1[TW] = {0.f,0.f,0.f,0.f};
  __syncthreads(); STAGE_NAT(w1, 128, 0);  __syncthreads();
  MV_HALF(res0, hm0, hm1);
  __syncthreads(); STAGE_NAT(w1, 128, 64); __syncthreads();
  MV_HALF(res1, hm0, hm1);
  {
    float ba = b1[lane], bb = b1[lane + 64];
    _Pragma("unroll")
    for (int lt = 0; lt < TW; ++lt) {
      float v0 = hm0[lt] + ba, v1 = hm1[lt] + bb;
      hm0[lt] = 0.5f*v0*(1.f + erff(v0*0.70710678118654752f));
      hm1[lt] = 0.5f*v1*(1.f + erff(v1*0.70710678118654752f));
    }
  }

  // ---- P7: m = hmid @ w2 + b2 ; + res ; LN2 ; store ----
  float m0[TW] = {0.f,0.f,0.f,0.f}, m1[TW] = {0.f,0.f,0.f,0.f};
  __syncthreads(); STAGE_NAT(w2, 128, 0);  __syncthreads();
  MV_HALF(hm0, m0, m1);
  __syncthreads(); STAGE_NAT(w2, 128, 64); __syncthreads();
  MV_HALF(hm1, m0, m1);
  {
    float ba = b2[lane],  bb = b2[lane + 64];
    float ga = g2[lane],  gb = g2[lane + 64];
    float ca = bb2[lane], cb = bb2[lane + 64];
    _Pragma("unroll")
    for (int lt = 0; lt < TW; ++lt) {
      float v0 = m0[lt] + ba + res0[lt];
      float v1 = m1[lt] + bb + res1[lt];
      float s  = wred_sum(v0 + v1);
      float sq = wred_sum(v0*v0 + v1*v1);
      float mu = s * 0.0078125f;
      float var = sq * 0.0078125f - mu*mu;
      float rstd = rsqrtf(var + 1e-5f);
      int tok = tb + ltb + lt;
      outp[(size_t)tok*128 + lane]      = (v0 - mu)*rstd*ga + ca;
      outp[(size_t)tok*128 + 64 + lane] = (v1 - mu)*rstd*gb + cb;
    }
  }
}

extern "C" void kernel_launch(void* const* d_in, const int* in_sizes, int n_in,
                              void* d_out, int out_size, void* d_ws, size_t ws_size,
                              hipStream_t stream) {
  const float* xq  = (const float*)d_in[0];
  const float* kv  = (const float*)d_in[1];
  const float* wkv = (const float*)d_in[2];
  const float* wq  = (const float*)d_in[3];
  const float* wmh = (const float*)d_in[4];
  const float* bmh = (const float*)d_in[5];
  const float* w1  = (const float*)d_in[6];
  const float* b1  = (const float*)d_in[7];
  const float* w2  = (const float*)d_in[8];
  const float* b2  = (const float*)d_in[9];
  const float* g1  = (const float*)d_in[10];
  const float* bb1 = (const float*)d_in[11];
  const float* g2  = (const float*)d_in[12];
  const float* bb2 = (const float*)d_in[13];

  const int tokens = 32768;           // B*N
  dim3 grid(tokens / TB), block(256);
  ca_fused<<<grid, block, 0, stream>>>(xq, kv, wkv, wq, wmh, bmh,
                                       w1, b1, w2, b2, g1, bb1, g2, bb2,
                                       (float*)d_out);
}

// Round 2
// 76.233 us; speedup vs baseline: 3.9463x; 3.9463x over previous
//
#include <hip/hip_runtime.h>
#include <hip/hip_fp16.h>

typedef _Float16 f16x8 __attribute__((ext_vector_type(8)));
typedef float f32x4 __attribute__((ext_vector_type(4)));
typedef unsigned int uint32;

#define LDW 136   // row stride in halves for 128-wide LDS tiles (272B: 2-way bank alias = free)
#define TB  16    // tokens per block

// wait only lgkmcnt(0): vmcnt=63, expcnt=7, lgkmcnt=0  -> 0xC07F  (keeps prefetch loads in flight)
#define WAITLGKM() do { __builtin_amdgcn_s_waitcnt(0xC07F); __builtin_amdgcn_sched_barrier(0); } while(0)

__device__ __forceinline__ uint32 pk2f(float a, float b) {
  __half2 h = __floats2half2_rn(a, b);
  return *reinterpret_cast<uint32*>(&h);
}
__device__ __forceinline__ float bcast(float v, int sl) {
  return __int_as_float(__builtin_amdgcn_readlane(__float_as_int(v), sl));
}
__device__ __forceinline__ float wred_sum(float v) {
  v += __shfl_xor(v, 32); v += __shfl_xor(v, 16); v += __shfl_xor(v, 8);
  v += __shfl_xor(v, 4);  v += __shfl_xor(v, 2);  v += __shfl_xor(v, 1);
  return v;
}
__device__ __forceinline__ f16x8 ldsv8(const __half* p) {
  return *reinterpret_cast<const f16x8*>(p);   // 16B-aligned by construction -> ds_read_b128
}
__device__ __forceinline__ f32x4 mfma16(f16x8 a, f16x8 b, f32x4 c) {
  return __builtin_amdgcn_mfma_f32_16x16x32_f16(a, b, c, 0, 0, 0);
}

// ---- workspace layout (halves) ----
#define OFF_WQ   0          // wqT  [c 128][k 128] : wq[k][c]
#define OFF_WK2  16384      // wk2  [h 4][i 128][d 40] : wkv[i][h*32+d] (d<32, pad 0)
#define OFF_WV   36864      // wvT  [c 128][k 128] : wkv[k][128+c]
#define OFF_WMH  53248      // wmhT
#define OFF_W1   69632      // w1T
#define OFF_W2   86016      // w2T
#define WS_HALVES 102400

__global__ void prep_weights(const float* __restrict__ wq, const float* __restrict__ wkv,
                             const float* __restrict__ wmh, const float* __restrict__ w1,
                             const float* __restrict__ w2, __half* __restrict__ ws) {
  int idx = blockIdx.x * 256 + threadIdx.x;
  if (idx >= WS_HALVES) return;
  float v;
  if (idx < OFF_WK2) {
    int t = idx, c = t >> 7, k = t & 127;
    v = wq[k * 128 + c];
  } else if (idx < OFF_WV) {
    int t = idx - OFF_WK2;
    int d = t % 40, row = t / 40;            // row = h*128 + i
    int h = row >> 7, i = row & 127;
    v = (d < 32) ? wkv[i * 256 + h * 32 + d] : 0.f;
  } else if (idx < OFF_WMH) {
    int t = idx - OFF_WV, c = t >> 7, k = t & 127;
    v = wkv[k * 256 + 128 + c];
  } else if (idx < OFF_W1) {
    int t = idx - OFF_WMH, c = t >> 7, k = t & 127;
    v = wmh[k * 128 + c];
  } else if (idx < OFF_W2) {
    int t = idx - OFF_W1, c = t >> 7, k = t & 127;
    v = w1[k * 128 + c];
  } else {
    int t = idx - OFF_W2, c = t >> 7, k = t & 127;
    v = w2[k * 128 + c];
  }
  ws[idx] = __float2half_rn(v);
}

// stage full 128x128 f16 (c-major) matrix into WBUF (stride LDW)
#define STAGE_W(GOFF) do {                                                       \
  const uint4* src_ = reinterpret_cast<const uint4*>(wsv + (GOFF));              \
  _Pragma("unroll")                                                              \
  for (int r_ = 0; r_ < 8; ++r_) {                                               \
    int idx_ = r_ * 256 + tid;                                                   \
    int c_ = idx_ >> 4, ko_ = (idx_ & 15) * 8;                                   \
    *reinterpret_cast<uint4*>(&WBUF[c_ * LDW + ko_]) = src_[idx_];               \
  } } while (0)

// stage one i-half of wk2: LDS [h 4][i 64][d 40]
#define STAGE_W2(IH) do {                                                        \
  const uint4* src_ = reinterpret_cast<const uint4*>(wsv + OFF_WK2);             \
  _Pragma("unroll")                                                              \
  for (int r_ = 0; r_ < 5; ++r_) {                                               \
    int idx_ = r_ * 256 + tid;                                                   \
    int h_ = idx_ / 320, rem_ = idx_ - h_ * 320;                                 \
    *reinterpret_cast<uint4*>(&WBUF[h_ * 2560 + rem_ * 8]) =                     \
        src_[h_ * 640 + (IH) * 320 + rem_];                                      \
  } } while (0)

// one 16x16 output tile, K=128: A rows = tokens, B = WBUF cols (NT*16..+15)
#define GEMM_TILE(AT, NT, ACC) do {                                              \
  _Pragma("unroll")                                                              \
  for (int ks_ = 0; ks_ < 4; ++ks_) {                                            \
    f16x8 a_ = ldsv8(&(AT)[fr * LDW + ks_ * 32 + fq * 8]);                       \
    f16x8 b_ = ldsv8(&WBUF[((NT) * 16 + fr) * LDW + ks_ * 32 + fq * 8]);         \
    ACC = mfma16(a_, b_, ACC);                                                   \
  } } while (0)

__device__ __forceinline__ void stc(__half* base, int col, int r0, f32x4 a) {
#pragma unroll
  for (int r = 0; r < 4; ++r) base[(r0 + r) * LDW + col] = __float2half_rn(a[r]);
}

__global__ void __launch_bounds__(256, 2) ca_mfma(
    const float* __restrict__ xq, const float* __restrict__ kvin,
    const __half* __restrict__ wsv,
    const float* __restrict__ bmh, const float* __restrict__ b1,
    const float* __restrict__ b2,
    const float* __restrict__ g1, const float* __restrict__ bb1,
    const float* __restrict__ g2, const float* __restrict__ bb2,
    float* __restrict__ outp)
{
  __shared__ __half WBUF[128 * LDW];   // 34816 B; P2 aliases as [4][64][40]
  __shared__ __half QWC[64 * LDW];     // 17408 B: qw/ctx rows [h*16+tok]; later Y/RES/H/V quadrants
  __shared__ __half UBUF[3 * TB * LDW];// 13056 B: Xh | Qb | Ob ; P3 KV per wave at wv*1088

  const int tid = threadIdx.x;
  const int wv = tid >> 6, lane = tid & 63;
  const int fr = lane & 15, fq = lane >> 4;   // MFMA frag row / k-group
  const int tb = blockIdx.x * TB;
  const int ltb = wv * 4;

  __half* Xh = UBUF;              // P1 A-tile; H in P6/P7
  __half* Qb = UBUF + 2176;       // Q (P1->P2)
  __half* Ob = UBUF + 4352;       // OUT (P4->P5)
  __half* Yb  = QWC;              // y   (P5)  rows 0..15
  __half* RESb = QWC + 16 * LDW;  // res (P5->P7) rows 16..31
  __half* Hb   = QWC + 32 * LDW;  // gelu out (P6->P7)
  __half* Vb   = QWC + 48 * LDW;  // pre-LN2 (P7)

  const f32x4 ZZ = {0.f, 0.f, 0.f, 0.f};

  // ---- Xh (f16, stride LDW) + stage WqT ----
  {
    int tok = tid >> 4, ko = (tid & 15) * 8;
    const float4* s0 = reinterpret_cast<const float4*>(xq + (size_t)(tb + tok) * 128 + ko);
    float4 a = s0[0], b = s0[1];
    uint4 u; u.x = pk2f(a.x, a.y); u.y = pk2f(a.z, a.w);
    u.z = pk2f(b.x, b.y); u.w = pk2f(b.z, b.w);
    *reinterpret_cast<uint4*>(&Xh[tok * LDW + ko]) = u;
  }
  STAGE_W(OFF_WQ);
  __syncthreads();

  // ---- P1: Q = Xh @ Wq ----
  {
    f32x4 aA = ZZ, aB = ZZ;
    GEMM_TILE(Xh, wv, aA);
    GEMM_TILE(Xh, 4 + wv, aB);
    stc(Qb, wv * 16 + fr, fq * 4, aA);
    stc(Qb, 64 + wv * 16 + fr, fq * 4, aB);
  }
  __syncthreads();

  // ---- P2: qw[h][tok][i] = sum_d q[tok][h*32+d] * wkv[i][h*32+d] (wave = head) ----
#pragma unroll 1
  for (int ih = 0; ih < 2; ++ih) {
    STAGE_W2(ih);
    __syncthreads();
    f16x8 aq = ldsv8(&Qb[fr * LDW + wv * 32 + fq * 8]);
#pragma unroll
    for (int nt = 0; nt < 4; ++nt) {
      f16x8 b = ldsv8(&WBUF[wv * 2560 + (nt * 16 + fr) * 40 + fq * 8]);
      f32x4 acc = mfma16(aq, b, ZZ);
      stc(QWC + wv * 16 * LDW, ih * 64 + nt * 16 + fr, fq * 4, acc);
    }
    __syncthreads();
  }

  // ---- stage WvT (not used by P3), then wave-local P3 ----
  STAGE_W(OFF_WV);
  {
    const int p = lane & 31, hh = p >> 3, kk = p & 7, hf = lane >> 5;
    __half* kvw = UBUF + wv * 1088;   // per-wave KV tile [8][LDW], slots 0-1 (Xh/Qb dead)
    float4 pre[4];
    {
      const float4* kv4 = reinterpret_cast<const float4*>(kvin + (size_t)(tb + ltb) * 1024);
#pragma unroll
      for (int r = 0; r < 4; ++r) pre[r] = kv4[lane + r * 64];
    }
#pragma unroll 1
    for (int lt = 0; lt < 4; ++lt) {
      const int ltok = ltb + lt;
      WAITLGKM();   // prior iter's ds_reads of kvw done (WAR) before overwrite
#pragma unroll
      for (int r = 0; r < 4; ++r) {
        int idx = lane + r * 64, k = idx >> 5, i4 = (idx & 31) * 4;
        uint2 u; u.x = pk2f(pre[r].x, pre[r].y); u.y = pk2f(pre[r].z, pre[r].w);
        *reinterpret_cast<uint2*>(&kvw[k * LDW + i4]) = u;
      }
      if (lt < 3) {   // prefetch next token's kv while we compute this one
        const float4* kv4 = reinterpret_cast<const float4*>(kvin + (size_t)(tb + ltok + 1) * 1024);
#pragma unroll
        for (int r = 0; r < 4; ++r) pre[r] = kv4[lane + r * 64];
      }
      WAITLGKM();   // kv writes visible to all lanes of this wave
      // sim: lane -> (hf, hh, kk); dot over 64 i in f16 pairs
      const __half2* q2 = reinterpret_cast<const __half2*>(&QWC[(hh * 16 + ltok) * LDW + hf * 64]);
      const __half2* k2 = reinterpret_cast<const __half2*>(&kvw[kk * LDW + hf * 64]);
      __half2 s0 = __floats2half2_rn(0.f, 0.f), s1 = s0;
#pragma unroll
      for (int ii = 0; ii < 32; ii += 2) {
        s0 = __hfma2(q2[ii], k2[ii], s0);
        s1 = __hfma2(q2[ii + 1], k2[ii + 1], s1);
      }
      s0 = __hadd2(s0, s1);
      float acc = (__low2float(s0) + __high2float(s0)) * 0.17677669529663687f;
      acc += __shfl_xor(acc, 32);
      float m = acc;
      m = fmaxf(m, __shfl_xor(m, 1));
      m = fmaxf(m, __shfl_xor(m, 2));
      m = fmaxf(m, __shfl_xor(m, 4));
      float e = __expf(acc - m);
      float sden = e;
      sden += __shfl_xor(sden, 1); sden += __shfl_xor(sden, 2); sden += __shfl_xor(sden, 4);
      float at = __fdividef(e, sden);   // lane p holds attn[h=p>>3][k=p&7] (both halves)
      // ctx[h][i] = sum_k attn*kv ; overwrite qw rows of this token
      float kva[8], kvb[8];
#pragma unroll
      for (int k = 0; k < 8; ++k) {
        kva[k] = __half2float(kvw[k * LDW + lane]);
        kvb[k] = __half2float(kvw[k * LDW + 64 + lane]);
      }
#pragma unroll
      for (int h = 0; h < 4; ++h) {
        float c0 = 0.f, c1 = 0.f;
#pragma unroll
        for (int k = 0; k < 8; ++k) {
          float a = bcast(at, h * 8 + k);
          c0 = fmaf(a, kva[k], c0);
          c1 = fmaf(a, kvb[k], c1);
        }
        QWC[(h * 16 + ltok) * LDW + lane] = __float2half_rn(c0);
        QWC[(h * 16 + ltok) * LDW + 64 + lane] = __float2half_rn(c1);
      }
    }
  }
  __syncthreads();

  // ---- P4: out[tok][c] = sum_i ctx[h(c)][tok][i] * wkv[i][128+c] ----
  {
    const int h1 = wv >> 1, h2 = 2 + (wv >> 1);
    f32x4 a1c = ZZ, a2c = ZZ;
#pragma unroll
    for (int ks = 0; ks < 4; ++ks) {
      f16x8 a1 = ldsv8(&QWC[(h1 * 16 + fr) * LDW + ks * 32 + fq * 8]);
      f16x8 b1 = ldsv8(&WBUF[(wv * 16 + fr) * LDW + ks * 32 + fq * 8]);
      a1c = mfma16(a1, b1, a1c);
      f16x8 a2 = ldsv8(&QWC[(h2 * 16 + fr) * LDW + ks * 32 + fq * 8]);
      f16x8 b2 = ldsv8(&WBUF[(64 + wv * 16 + fr) * LDW + ks * 32 + fq * 8]);
      a2c = mfma16(a2, b2, a2c);
    }
    __syncthreads();              // QWC qw/ctx reads done everywhere -> arena reuse ok
    stc(Ob, wv * 16 + fr, fq * 4, a1c);
    stc(Ob, 64 + wv * 16 + fr, fq * 4, a2c);
  }
  __syncthreads();

  // ---- P5: y = out @ wmh ----
  STAGE_W(OFF_WMH);
  __syncthreads();
  {
    f32x4 aA = ZZ, aB = ZZ;
    GEMM_TILE(Ob, wv, aA);
    GEMM_TILE(Ob, 4 + wv, aB);
    stc(Yb, wv * 16 + fr, fq * 4, aA);
    stc(Yb, 64 + wv * 16 + fr, fq * 4, aB);
  }
  __syncthreads();

  // ---- LN1 + residual (writes RESb) ; stage W1 ----
  {
    float ba = bmh[lane], bb = bmh[lane + 64];
    float ga = g1[lane], gb = g1[lane + 64];
    float ca = bb1[lane], cb = bb1[lane + 64];
#pragma unroll
    for (int lt = 0; lt < 4; ++lt) {
      int row = ltb + lt, tok = tb + row;
      float v0 = __half2float(Yb[row * LDW + lane]) + ba;
      float v1 = __half2float(Yb[row * LDW + 64 + lane]) + bb;
      float s = wred_sum(v0 + v1);
      float sq = wred_sum(v0 * v0 + v1 * v1);
      float mu = s * 0.0078125f;
      float var = sq * 0.0078125f - mu * mu;
      float rstd = rsqrtf(var + 1e-5f);
      float x0 = xq[(size_t)tok * 128 + lane];
      float x1 = xq[(size_t)tok * 128 + 64 + lane];
      RESb[row * LDW + lane] = __float2half_rn((v0 - mu) * rstd * ga + ca + x0);
      RESb[row * LDW + 64 + lane] = __float2half_rn((v1 - mu) * rstd * gb + cb + x1);
    }
  }
  STAGE_W(OFF_W1);
  __syncthreads();

  // ---- P6: h = gelu(res @ w1 + b1) ----
  {
    f32x4 aA = ZZ, aB = ZZ;
    GEMM_TILE(RESb, wv, aA);
    GEMM_TILE(RESb, 4 + wv, aB);
    int c0 = wv * 16 + fr, c1 = 64 + wv * 16 + fr;
    float b1a = b1[c0], b1b = b1[c1];
#pragma unroll
    for (int r = 0; r < 4; ++r) {
      float v0 = aA[r] + b1a, v1 = aB[r] + b1b;
      v0 = 0.5f * v0 * (1.f + erff(v0 * 0.70710678118654752f));
      v1 = 0.5f * v1 * (1.f + erff(v1 * 0.70710678118654752f));
      Hb[(fq * 4 + r) * LDW + c0] = __float2half_rn(v0);
      Hb[(fq * 4 + r) * LDW + c1] = __float2half_rn(v1);
    }
  }
  __syncthreads();
  STAGE_W(OFF_W2);
  __syncthreads();

  // ---- P7: v = h @ w2 + b2 + res ----
  {
    f32x4 aA = ZZ, aB = ZZ;
    GEMM_TILE(Hb, wv, aA);
    GEMM_TILE(Hb, 4 + wv, aB);
    int c0 = wv * 16 + fr, c1 = 64 + wv * 16 + fr;
    float b2a = b2[c0], b2b = b2[c1];
#pragma unroll
    for (int r = 0; r < 4; ++r) {
      int row = fq * 4 + r;
      float v0 = aA[r] + b2a + __half2float(RESb[row * LDW + c0]);
      float v1 = aB[r] + b2b + __half2float(RESb[row * LDW + c1]);
      Vb[row * LDW + c0] = __float2half_rn(v0);
      Vb[row * LDW + c1] = __float2half_rn(v1);
    }
  }
  __syncthreads();

  // ---- LN2 + store ----
  {
    float ga = g2[lane], gb = g2[lane + 64];
    float ca = bb2[lane], cb = bb2[lane + 64];
#pragma unroll
    for (int lt = 0; lt < 4; ++lt) {
      int row = ltb + lt, tok = tb + row;
      float v0 = __half2float(Vb[row * LDW + lane]);
      float v1 = __half2float(Vb[row * LDW + 64 + lane]);
      float s = wred_sum(v0 + v1);
      float sq = wred_sum(v0 * v0 + v1 * v1);
      float mu = s * 0.0078125f;
      float var = sq * 0.0078125f - mu * mu;
      float rstd = rsqrtf(var + 1e-5f);
      outp[(size_t)tok * 128 + lane] = (v0 - mu) * rstd * ga + ca;
      outp[(size_t)tok * 128 + 64 + lane] = (v1 - mu) * rstd * gb + cb;
    }
  }
}

extern "C" void kernel_launch(void* const* d_in, const int* in_sizes, int n_in,
                              void* d_out, int out_size, void* d_ws, size_t ws_size,
                              hipStream_t stream) {
  const float* xq = (const float*)d_in[0];
  const float* kv = (const float*)d_in[1];
  const float* wkv = (const float*)d_in[2];
  const float* wq = (const float*)d_in[3];
  const float* wmh = (const float*)d_in[4];
  const float* bmh = (const float*)d_in[5];
  const float* w1 = (const float*)d_in[6];
  const float* b1 = (const float*)d_in[7];
  const float* w2 = (const float*)d_in[8];
  const float* b2 = (const float*)d_in[9];
  const float* g1 = (const float*)d_in[10];
  const float* bb1 = (const float*)d_in[11];
  const float* g2 = (const float*)d_in[12];
  const float* bb2 = (const float*)d_in[13];
  __half* ws = (__half*)d_ws;

  prep_weights<<<(WS_HALVES + 255) / 256, 256, 0, stream>>>(wq, wkv, wmh, w1, w2, ws);

  const int tokens = 32768;
  ca_mfma<<<tokens / TB, 256, 0, stream>>>(xq, kv, ws, bmh, b1, b2,
                                           g1, bb1, g2, bb2, (float*)d_out);
}

// Round 3
// 65.549 us; speedup vs baseline: 4.5894x; 1.1630x over previous
//
#include <hip/hip_runtime.h>
#include <hip/hip_fp16.h>

typedef _Float16 f16x8 __attribute__((ext_vector_type(8)));
typedef float f32x4 __attribute__((ext_vector_type(4)));
typedef unsigned int uint32;

#define LDW 136   // row stride in halves (272B: 16B-aligned, ~2-way bank alias = free)
#define TB  16    // tokens per block

// wait only lgkmcnt(0): vmcnt=63, expcnt=7, lgkmcnt=0 -> 0xC07F (keeps global loads in flight)
#define WAITLGKM() do { __builtin_amdgcn_s_waitcnt(0xC07F); __builtin_amdgcn_sched_barrier(0); } while(0)

__device__ __forceinline__ uint32 pk2f(float a, float b) {
  __half2 h = __floats2half2_rn(a, b);
  return *reinterpret_cast<uint32*>(&h);
}
__device__ __forceinline__ float bcast(float v, int sl) {
  return __int_as_float(__builtin_amdgcn_readlane(__float_as_int(v), sl));
}
__device__ __forceinline__ float wred_sum(float v) {
  v += __shfl_xor(v, 32); v += __shfl_xor(v, 16); v += __shfl_xor(v, 8);
  v += __shfl_xor(v, 4);  v += __shfl_xor(v, 2);  v += __shfl_xor(v, 1);
  return v;
}
__device__ __forceinline__ f16x8 ldsv8(const __half* p) {
  return *reinterpret_cast<const f16x8*>(p);   // 16B-aligned -> ds_read_b128
}
__device__ __forceinline__ f32x4 mfma16(f16x8 a, f16x8 b, f32x4 c) {
  return __builtin_amdgcn_mfma_f32_16x16x32_f16(a, b, c, 0, 0, 0);
}
__device__ __forceinline__ void stc(__half* base, int col, int r0, f32x4 a) {
#pragma unroll
  for (int r = 0; r < 4; ++r) base[(r0 + r) * LDW + col] = __float2half_rn(a[r]);
}

// ---- workspace layout (halves) ----
#define OFF_WQ   0          // wqT  [c 128][k 128] : wq[k][c]
#define OFF_WK2  16384      // wk2  [h 4][i 128][d 40] : wkv[i][h*32+d] (d<32, pad 0)
#define OFF_WV   36864      // wvT  [c 128][k 128] : wkv[k][128+c]
#define OFF_WMH  53248      // wmhT
#define OFF_W1   69632      // w1T
#define OFF_W2   86016      // w2T
#define WS_HALVES 102400

__global__ void prep_weights(const float* __restrict__ wq, const float* __restrict__ wkv,
                             const float* __restrict__ wmh, const float* __restrict__ w1,
                             const float* __restrict__ w2, __half* __restrict__ ws) {
  int idx = blockIdx.x * 256 + threadIdx.x;
  if (idx >= WS_HALVES) return;
  float v;
  if (idx < OFF_WK2) {
    int t = idx, c = t >> 7, k = t & 127;
    v = wq[k * 128 + c];
  } else if (idx < OFF_WV) {
    int t = idx - OFF_WK2;
    int d = t % 40, row = t / 40;            // row = h*128 + i
    int h = row >> 7, i = row & 127;
    v = (d < 32) ? wkv[i * 256 + h * 32 + d] : 0.f;
  } else if (idx < OFF_WMH) {
    int t = idx - OFF_WV, c = t >> 7, k = t & 127;
    v = wkv[k * 256 + 128 + c];
  } else if (idx < OFF_W1) {
    int t = idx - OFF_WMH, c = t >> 7, k = t & 127;
    v = wmh[k * 128 + c];
  } else if (idx < OFF_W2) {
    int t = idx - OFF_W1, c = t >> 7, k = t & 127;
    v = w1[k * 128 + c];
  } else {
    int t = idx - OFF_W2, c = t >> 7, k = t & 127;
    v = w2[k * 128 + c];
  }
  ws[idx] = __float2half_rn(v);
}

// load B frags (2 col-tiles x 4 k-slices) of a c-major [128][128] f16 matrix at GOFF
#define LOADB2(GOFF, NT0, NT1, BF) do {                                          \
  _Pragma("unroll")                                                              \
  for (int t_ = 0; t_ < 2; ++t_) {                                               \
    int nt_ = t_ ? (NT1) : (NT0);                                                \
    _Pragma("unroll")                                                            \
    for (int ks_ = 0; ks_ < 4; ++ks_)                                            \
      BF[t_][ks_] = *reinterpret_cast<const f16x8*>(                             \
          wsv + (GOFF) + (nt_*16 + fr)*128 + ks_*32 + fq*8);                     \
  } } while (0)

// two 16x16 tiles sharing the A operand, K=128
#define GEMM2(AT, BF, ACC0, ACC1) do {                                           \
  _Pragma("unroll")                                                              \
  for (int ks_ = 0; ks_ < 4; ++ks_) {                                            \
    f16x8 a_ = ldsv8(&(AT)[fr * LDW + ks_ * 32 + fq * 8]);                       \
    ACC0 = mfma16(a_, BF[0][ks_], ACC0);                                         \
    ACC1 = mfma16(a_, BF[1][ks_], ACC1);                                         \
  } } while (0)

__global__ void __launch_bounds__(256, 4) ca_mfma(
    const float* __restrict__ xq, const float* __restrict__ kvin,
    const __half* __restrict__ wsv,
    const float* __restrict__ bmh, const float* __restrict__ b1,
    const float* __restrict__ b2,
    const float* __restrict__ g1, const float* __restrict__ bb1,
    const float* __restrict__ g2, const float* __restrict__ bb2,
    float* __restrict__ outp)
{
  __shared__ __half QWC[64 * LDW];      // 17408 B: qw/ctx rows [h*16+tok]; then Y/RES/H/V
  __shared__ __half UBUF[3 * TB * LDW]; // 13056 B: Xh | Qb | Ob ; P3 KV per wave at wv*1088

  const int tid = threadIdx.x;
  const int wv = tid >> 6, lane = tid & 63;
  const int fr = lane & 15, fq = lane >> 4;   // MFMA frag row / k-group
  const int tb = blockIdx.x * TB;
  const int ltb = wv * 4;

  __half* Xh = UBUF;
  __half* Qb = UBUF + 2176;
  __half* Ob = UBUF + 4352;
  __half* Yb   = QWC;
  __half* RESb = QWC + 16 * LDW;
  __half* Hb   = QWC + 32 * LDW;
  __half* Vb   = QWC + 48 * LDW;

  const f32x4 ZZ = {0.f, 0.f, 0.f, 0.f};

  // ---- entry: prefetch token-0 kv for this wave + P1's B frags ----
  float4 pre[4];
  {
    const float4* kv4 = reinterpret_cast<const float4*>(kvin + (size_t)(tb + ltb) * 1024);
#pragma unroll
    for (int r = 0; r < 4; ++r) pre[r] = kv4[lane + r * 64];
  }
  f16x8 bf[2][4];
  LOADB2(OFF_WQ, wv, 4 + wv, bf);

  // ---- Xh (f16, stride LDW) ----
  {
    int tok = tid >> 4, ko = (tid & 15) * 8;
    const float4* s0 = reinterpret_cast<const float4*>(xq + (size_t)(tb + tok) * 128 + ko);
    float4 a = s0[0], b = s0[1];
    uint4 u; u.x = pk2f(a.x, a.y); u.y = pk2f(a.z, a.w);
    u.z = pk2f(b.x, b.y); u.w = pk2f(b.z, b.w);
    *reinterpret_cast<uint4*>(&Xh[tok * LDW + ko]) = u;
  }
  __syncthreads();  // 1: Xh ready; bf(wq) + kv pre drained

  // ---- P1: Q = Xh @ Wq ----
  {
    f32x4 aA = ZZ, aB = ZZ;
    GEMM2(Xh, bf, aA, aB);
    stc(Qb, wv * 16 + fr, fq * 4, aA);
    stc(Qb, 64 + wv * 16 + fr, fq * 4, aB);
  }
  // issue P2's B (head wv's wk2 rows), K=32 tiles
  f16x8 bq[8];
#pragma unroll
  for (int nt = 0; nt < 8; ++nt)
    bq[nt] = *reinterpret_cast<const f16x8*>(
        wsv + OFF_WK2 + (wv * 128 + nt * 16 + fr) * 40 + fq * 8);
  __syncthreads();  // 2: Qb ready; bq drained

  // ---- P2: qw[wv][tok][i] = sum_d q[tok][wv*32+d] * wkv[i][wv*32+d] ----
  {
    f16x8 aq = ldsv8(&Qb[fr * LDW + wv * 32 + fq * 8]);
#pragma unroll
    for (int nt = 0; nt < 8; ++nt) {
      f32x4 acc = mfma16(aq, bq[nt], ZZ);
      stc(QWC + wv * 16 * LDW, nt * 16 + fr, fq * 4, acc);
    }
  }
  __syncthreads();  // 3: qw ready; Qb reads done (kvw may overwrite)

  // ---- P3: wave-local attention over this wave's 4 tokens ----
  {
    const int p = lane & 31, hh = p >> 3, kk = p & 7, hf = lane >> 5;
    __half* kvw = UBUF + wv * 1088;   // [8][LDW] per wave, aliases Xh/Qb (dead)
#pragma unroll 1
    for (int lt = 0; lt < 4; ++lt) {
      const int ltok = ltb + lt;
      WAITLGKM();   // prior iter's ds_reads of kvw done (WAR) before overwrite
#pragma unroll
      for (int r = 0; r < 4; ++r) {
        int idx = lane + r * 64, k = idx >> 5, i4 = (idx & 31) * 4;
        uint2 u; u.x = pk2f(pre[r].x, pre[r].y); u.y = pk2f(pre[r].z, pre[r].w);
        *reinterpret_cast<uint2*>(&kvw[k * LDW + i4]) = u;
      }
      if (lt < 3) {   // prefetch next token's kv
        const float4* kv4 = reinterpret_cast<const float4*>(kvin + (size_t)(tb + ltok + 1) * 1024);
#pragma unroll
        for (int r = 0; r < 4; ++r) pre[r] = kv4[lane + r * 64];
      }
      WAITLGKM();   // kv writes visible within wave
      const __half2* q2 = reinterpret_cast<const __half2*>(&QWC[(hh * 16 + ltok) * LDW + hf * 64]);
      const __half2* k2 = reinterpret_cast<const __half2*>(&kvw[kk * LDW + hf * 64]);
      __half2 s0 = __floats2half2_rn(0.f, 0.f), s1 = s0;
#pragma unroll
      for (int ii = 0; ii < 32; ii += 2) {
        s0 = __hfma2(q2[ii], k2[ii], s0);
        s1 = __hfma2(q2[ii + 1], k2[ii + 1], s1);
      }
      s0 = __hadd2(s0, s1);
      float acc = (__low2float(s0) + __high2float(s0)) * 0.17677669529663687f;
      acc += __shfl_xor(acc, 32);
      float m = acc;
      m = fmaxf(m, __shfl_xor(m, 1));
      m = fmaxf(m, __shfl_xor(m, 2));
      m = fmaxf(m, __shfl_xor(m, 4));
      float e = __expf(acc - m);
      float sden = e;
      sden += __shfl_xor(sden, 1); sden += __shfl_xor(sden, 2); sden += __shfl_xor(sden, 4);
      float at = __fdividef(e, sden);   // lane p holds attn[h=p>>3][k=p&7]
      float kva[8], kvb[8];
#pragma unroll
      for (int k = 0; k < 8; ++k) {
        kva[k] = __half2float(kvw[k * LDW + lane]);
        kvb[k] = __half2float(kvw[k * LDW + 64 + lane]);
      }
#pragma unroll
      for (int h = 0; h < 4; ++h) {
        float c0 = 0.f, c1 = 0.f;
#pragma unroll
        for (int k = 0; k < 8; ++k) {
          float a = bcast(at, h * 8 + k);
          c0 = fmaf(a, kva[k], c0);
          c1 = fmaf(a, kvb[k], c1);
        }
        QWC[(h * 16 + ltok) * LDW + lane] = __float2half_rn(c0);
        QWC[(h * 16 + ltok) * LDW + 64 + lane] = __float2half_rn(c1);
      }
    }
  }
  LOADB2(OFF_WV, wv, 4 + wv, bf);
  __syncthreads();  // 4: ctx ready; bf(wv) drained

  // ---- P4: out[tok][c] = sum_i ctx[h(c)][tok][i] * wvT[c][i] ----
  float xr0[4], xr1[4];   // residual x, issued early for LN1
#pragma unroll
  for (int lt = 0; lt < 4; ++lt) {
    int tok = tb + ltb + lt;
    xr0[lt] = xq[(size_t)tok * 128 + lane];
    xr1[lt] = xq[(size_t)tok * 128 + 64 + lane];
  }
  {
    const int h1 = wv >> 1, h2 = 2 + (wv >> 1);
    f32x4 a1c = ZZ, a2c = ZZ;
#pragma unroll
    for (int ks = 0; ks < 4; ++ks) {
      f16x8 a1 = ldsv8(&QWC[(h1 * 16 + fr) * LDW + ks * 32 + fq * 8]);
      a1c = mfma16(a1, bf[0][ks], a1c);
      f16x8 a2 = ldsv8(&QWC[(h2 * 16 + fr) * LDW + ks * 32 + fq * 8]);
      a2c = mfma16(a2, bf[1][ks], a2c);
    }
    stc(Ob, wv * 16 + fr, fq * 4, a1c);
    stc(Ob, 64 + wv * 16 + fr, fq * 4, a2c);
  }
  LOADB2(OFF_WMH, wv, 4 + wv, bf);
  __syncthreads();  // 5: Ob ready; QWC reads done; bf(wmh) drained

  // ---- P5: y = out @ wmh ----
  {
    f32x4 aA = ZZ, aB = ZZ;
    GEMM2(Ob, bf, aA, aB);
    stc(Yb, wv * 16 + fr, fq * 4, aA);
    stc(Yb, 64 + wv * 16 + fr, fq * 4, aB);
  }
  LOADB2(OFF_W1, wv, 4 + wv, bf);
  __syncthreads();  // 6: Yb ready; bf(w1) drained

  // ---- LN1 + residual -> RESb ----
  {
    float ba = bmh[lane], bb = bmh[lane + 64];
    float ga = g1[lane], gb = g1[lane + 64];
    float ca = bb1[lane], cb = bb1[lane + 64];
#pragma unroll
    for (int lt = 0; lt < 4; ++lt) {
      int row = ltb + lt;
      float v0 = __half2float(Yb[row * LDW + lane]) + ba;
      float v1 = __half2float(Yb[row * LDW + 64 + lane]) + bb;
      float s = wred_sum(v0 + v1);
      float sq = wred_sum(v0 * v0 + v1 * v1);
      float mu = s * 0.0078125f;
      float var = sq * 0.0078125f - mu * mu;
      float rstd = rsqrtf(var + 1e-5f);
      RESb[row * LDW + lane] = __float2half_rn((v0 - mu) * rstd * ga + ca + xr0[lt]);
      RESb[row * LDW + 64 + lane] = __float2half_rn((v1 - mu) * rstd * gb + cb + xr1[lt]);
    }
  }
  __syncthreads();  // 7: RESb ready

  // ---- P6: h = gelu(res @ w1 + b1) ----
  {
    f32x4 aA = ZZ, aB = ZZ;
    GEMM2(RESb, bf, aA, aB);
    int c0 = wv * 16 + fr, c1 = 64 + wv * 16 + fr;
    float b1a = b1[c0], b1b = b1[c1];
#pragma unroll
    for (int r = 0; r < 4; ++r) {
      float v0 = aA[r] + b1a, v1 = aB[r] + b1b;
      v0 = 0.5f * v0 * (1.f + erff(v0 * 0.70710678118654752f));
      v1 = 0.5f * v1 * (1.f + erff(v1 * 0.70710678118654752f));
      Hb[(fq * 4 + r) * LDW + c0] = __float2half_rn(v0);
      Hb[(fq * 4 + r) * LDW + c1] = __float2half_rn(v1);
    }
  }
  LOADB2(OFF_W2, wv, 4 + wv, bf);
  __syncthreads();  // 8: Hb ready; bf(w2) drained

  // ---- P7: v = h @ w2 + b2 + res ----
  {
    f32x4 aA = ZZ, aB = ZZ;
    GEMM2(Hb, bf, aA, aB);
    int c0 = wv * 16 + fr, c1 = 64 + wv * 16 + fr;
    float b2a = b2[c0], b2b = b2[c1];
#pragma unroll
    for (int r = 0; r < 4; ++r) {
      int row = fq * 4 + r;
      float v0 = aA[r] + b2a + __half2float(RESb[row * LDW + c0]);
      float v1 = aB[r] + b2b + __half2float(RESb[row * LDW + c1]);
      Vb[row * LDW + c0] = __float2half_rn(v0);
      Vb[row * LDW + c1] = __float2half_rn(v1);
    }
  }
  __syncthreads();  // 9: Vb ready

  // ---- LN2 + store ----
  {
    float ga = g2[lane], gb = g2[lane + 64];
    float ca = bb2[lane], cb = bb2[lane + 64];
#pragma unroll
    for (int lt = 0; lt < 4; ++lt) {
      int row = ltb + lt, tok = tb + row;
      float v0 = __half2float(Vb[row * LDW + lane]);
      float v1 = __half2float(Vb[row * LDW + 64 + lane]);
      float s = wred_sum(v0 + v1);
      float sq = wred_sum(v0 * v0 + v1 * v1);
      float mu = s * 0.0078125f;
      float var = sq * 0.0078125f - mu * mu;
      float rstd = rsqrtf(var + 1e-5f);
      outp[(size_t)tok * 128 + lane] = (v0 - mu) * rstd * ga + ca;
      outp[(size_t)tok * 128 + 64 + lane] = (v1 - mu) * rstd * gb + cb;
    }
  }
}

extern "C" void kernel_launch(void* const* d_in, const int* in_sizes, int n_in,
                              void* d_out, int out_size, void* d_ws, size_t ws_size,
                              hipStream_t stream) {
  const float* xq = (const float*)d_in[0];
  const float* kv = (const float*)d_in[1];
  const float* wkv = (const float*)d_in[2];
  const float* wq = (const float*)d_in[3];
  const float* wmh = (const float*)d_in[4];
  const float* bmh = (const float*)d_in[5];
  const float* w1 = (const float*)d_in[6];
  const float* b1 = (const float*)d_in[7];
  const float* w2 = (const float*)d_in[8];
  const float* b2 = (const float*)d_in[9];
  const float* g1 = (const float*)d_in[10];
  const float* bb1 = (const float*)d_in[11];
  const float* g2 = (const float*)d_in[12];
  const float* bb2 = (const float*)d_in[13];
  __half* ws = (__half*)d_ws;

  prep_weights<<<(WS_HALVES + 255) / 256, 256, 0, stream>>>(wq, wkv, wmh, w1, w2, ws);

  const int tokens = 32768;
  ca_mfma<<<tokens / TB, 256, 0, stream>>>(xq, kv, ws, bmh, b1, b2,
                                           g1, bb1, g2, bb2, (float*)d_out);
}